// Round 6
// baseline (322.323 us; speedup 1.0000x reference)
//
#include <hip/hip_runtime.h>
#include <hip/hip_fp16.h>

// ---------------------------------------------------------------------------
// RelGraphConv (basis-decomposed, right-norm, sum over relations) on MI355X.
//
//   h[d] = B0^T * A0[d] + B1^T * A1[d] + x[d]@Wl + bias,  ReLU
//   A_b[d] = sum_{edges e->d} (coeff[r_e][b]/deg[r_e][d]) * x[src_e]
// R16: quarter-wave 16-edge predicated gather: 100us.
// R17: edge-centric stream REGRESSED (serial chain). REVERTED.
// R18: dual-node interleave REGRESSED (occ 45%, dup-load waste). REVERTED.
// R19: LDS-staged recs + quarter-wave-owns-node, no shuffles: 97us.
//   Gather now LLC-duty-cycle bound (FETCH 148MB = L2->LLC, xb 25.6MB).
// R20: attack the stable ~185us non-gather block (never in top-5 counters):
//   (a) 3 scan launches -> 1 decoupled-lookback scan (ticket + status spin,
//       rocPRIM-style; AMD dispatches blocks in ticket order -> no deadlock).
//   (b) rank/packed ELIMINATED: fill places via atomicAdd(&cursor[d],1)
//       (recs order within a node becomes arbitrary -- f32 accumulation,
//       R17 proved order-independence passes). fused_pre atomics become
//       fire-and-forget; fill reads deg[r][d] directly for the norm.
//       Saves rank 2.4MB W+R, packed 3.2MB W + random R.
//   (c) gather_gemm launch_bounds (256,5)->(256,6) (VGPR 44, LDS 25.2KB
//       both fit 6 blocks/CU).
//   Launches 7 -> 5.
// ---------------------------------------------------------------------------

#define DFEAT 128
#define NREL 8
#define ALDA 264   // LDS agg row stride in ushorts (256 data + 8 pad)
#define ECAP 1024  // staged-recs capacity (block edge count ~Poisson(384))

typedef __attribute__((ext_vector_type(8))) short bf16x8;
typedef __attribute__((ext_vector_type(4))) float f32x4;
typedef __attribute__((ext_vector_type(2))) float f32x2;

__device__ __forceinline__ ushort f2bf(float f) {
    unsigned u = __float_as_uint(f);
    u += 0x7FFF + ((u >> 16) & 1);          // round-to-nearest-even
    return (ushort)(u >> 16);
}
__device__ __forceinline__ float bflo(unsigned u) { return __uint_as_float(u << 16); }
__device__ __forceinline__ float bfhi(unsigned u) { return __uint_as_float(u & 0xFFFF0000u); }
__device__ __forceinline__ unsigned pack2bf(float lo, float hi) {
    return (unsigned)f2bf(lo) | ((unsigned)f2bf(hi) << 16);
}

// Fused: count (fire-and-forget atomics) + convert_x + build_w2T (BW-bound).
// deg must be pre-zeroed. w2T[j][k]: k<256 -> bases[k>>7][k&127][j],
// else loopw[k-256][j].
__global__ void fused_pre(const int* __restrict__ dst, int* __restrict__ deg,
                          const float* __restrict__ x, ushort* __restrict__ xb,
                          const float* __restrict__ bases, const float* __restrict__ loopw,
                          ushort* __restrict__ w2T,
                          int RE, int E, int N, int n4) {
    const int stride = gridDim.x * blockDim.x;
    const int t0 = blockIdx.x * blockDim.x + threadIdx.x;
    for (int i = t0; i < RE; i += stride) {
        int r = i / E;
        int d = dst[i];
        atomicAdd(&deg[r * N + d], 1);      // no return value -> no round-trip
    }
    for (int i = t0; i < n4; i += stride) {
        float4 v = ((const float4*)x)[i];
        ushort4 o;
        o.x = f2bf(v.x); o.y = f2bf(v.y); o.z = f2bf(v.z); o.w = f2bf(v.w);
        ((ushort4*)xb)[i] = o;
    }
    for (int i = t0; i < 128 * 384; i += stride) {
        int j = i / 384, k = i % 384;
        float v = (k < 256) ? bases[(k >> 7) * DFEAT * DFEAT + (k & 127) * DFEAT + j]
                            : loopw[(k - 256) * DFEAT + j];
        w2T[i] = f2bf(v);
    }
}

// ---------------------------------------------------------------------------
// Single-pass decoupled-lookback scan. Block (ticket b) handles nodes
// [b*256, b*256+256): cnt[d] = sum_r deg[r][d]; inclusive block scan;
// publish aggregate (val<<2|1); lookback over predecessors; publish
// prefix (val<<2|2); write rowStart[d] = base + local_exclusive and
// cursor[d] = same. status/ticket zeroed by the same memset as deg.
// Totals <= RE = 1.2M < 2^21 -> fits in 30 bits above the 2 state bits.
// ---------------------------------------------------------------------------
__global__ void scan_onepass(const int* __restrict__ deg,
                             int* __restrict__ rowStart, int* __restrict__ cursor,
                             unsigned* __restrict__ status, int* __restrict__ ticket,
                             int N) {
    __shared__ int tsum[256];
    __shared__ int sbid;
    __shared__ int sbase;
    const int t = threadIdx.x;
    if (t == 0) sbid = atomicAdd(ticket, 1);
    __syncthreads();
    const int b = sbid;
    const int idx = b * 256 + t;

    int c = 0;
    if (idx < N) {
        #pragma unroll
        for (int r = 0; r < NREL; ++r) c += deg[r * N + idx];
    }
    tsum[t] = c; __syncthreads();
    for (int off = 1; off < 256; off <<= 1) {
        int x = 0;
        if (t >= off) x = tsum[t - off];
        __syncthreads();
        if (t >= off) tsum[t] += x;
        __syncthreads();
    }
    const int lexcl = tsum[t] - c;          // exclusive within block
    const int total = tsum[255];

    if (t == 0) {
        atomicExch(&status[b], ((unsigned)total << 2) | 1u);   // aggregate
        int base = 0;
        for (int p = b - 1; p >= 0; --p) {
            unsigned s;
            do { s = atomicOr(&status[p], 0u); } while ((s & 3u) == 0u);
            base += (int)(s >> 2);
            if ((s & 3u) == 2u) break;      // prefix found
        }
        atomicExch(&status[b], ((unsigned)(base + total) << 2) | 2u);  // prefix
        sbase = base;
    }
    __syncthreads();
    if (idx < N) {
        int rs = sbase + lexcl;
        rowStart[idx] = rs;
        cursor[idx]   = rs;
    }
}

// Placement via per-node cursor atomic. inv from deg[r][d] directly.
__global__ void fill_kernel(const int* __restrict__ src, const int* __restrict__ dst,
                            const float* __restrict__ coeff,
                            const int* __restrict__ deg, int* __restrict__ cursor,
                            uint2* __restrict__ recs, int RE, int E, int N) {
    int idx = blockIdx.x * blockDim.x + threadIdx.x;
    if (idx >= RE) return;
    int r = idx / E;
    int d = dst[idx];
    int dv = deg[r * N + d];                // >= 1 (this edge counted)
    float inv = 1.0f / (float)dv;
    int pos = atomicAdd(&cursor[d], 1);
    __half2 hc = __floats2half2_rn(coeff[2 * r] * inv, coeff[2 * r + 1] * inv);
    uint2 rec;
    rec.x = (unsigned)src[idx];
    rec.y = *(unsigned*)&hc;
    recs[pos] = rec;
}

// ---------------------------------------------------------------------------
// FUSED gather + GEMM. Block = 32 dst nodes, LDS 16.9KB agg + 8KB recs.
// Phase 0: stage rowStart[row0..row0+32] and recs[e0..e1) into LDS.
// Phase 1: quarter-wave qw owns nodes {qw, qw+16}; 16 lanes cover 128
//   feats; 8-edge rounds, rec from LDS (broadcast read), xb uint4 gather.
//   Accumulate f32; write c0 slice to agg[i][h*8], c1 to agg[i][128+h*8].
// Phase 2: out[32,128] = relu([aggLDS|xb][32,384] @ w2T^T + bias).
// ---------------------------------------------------------------------------
__global__ __launch_bounds__(256, 6) void gather_gemm(
    const uint2* __restrict__ recs, const int* __restrict__ rowStart,
    const ushort* __restrict__ xb,
    const ushort* __restrict__ w2T, const float* __restrict__ bias,
    float* __restrict__ out, int N, int RE) {
    __shared__ __align__(16) ushort agg[32 * ALDA];   // 16.9 KB
    __shared__ __align__(16) uint2 recsL[ECAP];       // 8 KB
    __shared__ int rsl[33];
    const int tid = threadIdx.x;
    const int wave = tid >> 6, lane = tid & 63;
    const int row0 = blockIdx.x * 32;

    // ---- phase 0: stage rowStarts + recs ----
    if (tid < 33) {
        int d = row0 + tid;
        rsl[tid] = (d < N) ? rowStart[d] : RE;
    }
    __syncthreads();
    const int e0 = rsl[0];
    const int cntE = rsl[32] - e0;
    const bool fits = (cntE <= ECAP);
    {
        const int lim = fits ? cntE : 0;
        for (int k = tid; k < lim; k += 256)
            recsL[k] = recs[e0 + k];
    }
    __syncthreads();

    // ---- phase 1: gather (quarter-wave per node) ----
    {
        const int qw = tid >> 4;        // quarter-wave id 0..15
        const int h  = tid & 15;        // feature slot: feats 8h..8h+7

        auto gatherNode = [&](int i, auto getRec) {
            const int s   = rsl[i] - e0;
            const int len = rsl[i + 1] - rsl[i];
            f32x2 A0 = {0.f,0.f}, A1 = {0.f,0.f}, A2 = {0.f,0.f}, A3 = {0.f,0.f};
            f32x2 B0 = {0.f,0.f}, B1 = {0.f,0.f}, B2 = {0.f,0.f}, B3 = {0.f,0.f};
            if (len > 0) {
                const int last = s + len - 1;
                for (int k = 0; k < len; k += 8) {
                    uint2 rc[8];
                    #pragma unroll
                    for (int j = 0; j < 8; ++j) {
                        int li = s + k + j;
                        rc[j] = getRec(li <= last ? li : last);
                    }
                    uint4 u[8];
                    #pragma unroll
                    for (int j = 0; j < 8; ++j)
                        u[j] = *(const uint4*)(xb + (size_t)rc[j].x * DFEAT + h * 8);
                    #pragma unroll
                    for (int j = 0; j < 8; ++j) {
                        bool v = (k + j) < len;
                        __half2 hc = *(__half2*)&rc[j].y;
                        float c0 = v ? __low2float(hc) : 0.f;
                        float c1 = v ? __high2float(hc) : 0.f;
                        f32x2 cc0 = {c0, c0}, cc1 = {c1, c1};
                        uint4 uu = u[j];
                        f32x2 f01 = {bflo(uu.x), bfhi(uu.x)};
                        f32x2 f23 = {bflo(uu.y), bfhi(uu.y)};
                        f32x2 f45 = {bflo(uu.z), bfhi(uu.z)};
                        f32x2 f67 = {bflo(uu.w), bfhi(uu.w)};
                        A0 += cc0 * f01; A1 += cc0 * f23; A2 += cc0 * f45; A3 += cc0 * f67;
                        B0 += cc1 * f01; B1 += cc1 * f23; B2 += cc1 * f45; B3 += cc1 * f67;
                    }
                }
            }
            uint4 w0, w1;
            w0.x = pack2bf(A0.x, A0.y); w0.y = pack2bf(A1.x, A1.y);
            w0.z = pack2bf(A2.x, A2.y); w0.w = pack2bf(A3.x, A3.y);
            w1.x = pack2bf(B0.x, B0.y); w1.y = pack2bf(B1.x, B1.y);
            w1.z = pack2bf(B2.x, B2.y); w1.w = pack2bf(B3.x, B3.y);
            *(uint4*)(agg + i * ALDA + h * 8)       = w0;   // c0 feats
            *(uint4*)(agg + i * ALDA + 128 + h * 8) = w1;   // c1 feats
        };

        if (fits) {
            #pragma unroll
            for (int p = 0; p < 2; ++p)
                gatherNode(qw + p * 16, [&](int li) { return recsL[li]; });
        } else {
            #pragma unroll
            for (int p = 0; p < 2; ++p)
                gatherNode(qw + p * 16, [&](int li) { return recs[e0 + li]; });
        }
    }
    __syncthreads();

    // ---- phase 2: GEMM (M=32) ----
    const int quad = lane >> 4, l16 = lane & 15;
    int arow[2];
    #pragma unroll
    for (int m = 0; m < 2; ++m) {
        int r = row0 + m * 16 + l16;
        arow[m] = (r < N) ? r : 0;
    }

    f32x4 zero = {0.f, 0.f, 0.f, 0.f};
    f32x4 acc[2][2] = {{zero, zero}, {zero, zero}};

    #pragma unroll
    for (int kt = 0; kt < 3; ++kt) {
        bf16x8 bq[4][2];
        #pragma unroll
        for (int t = 0; t < 4; ++t)
            #pragma unroll
            for (int g = 0; g < 2; ++g)
                bq[t][g] = *(const bf16x8*)(w2T + (size_t)(wave * 32 + g * 16 + l16) * 384
                                            + kt * 128 + t * 32 + quad * 8);
        #pragma unroll
        for (int m = 0; m < 2; ++m) {
            #pragma unroll
            for (int t = 0; t < 4; ++t) {
                bf16x8 a;
                if (kt < 2)
                    a = *(const bf16x8*)(agg + (m * 16 + l16) * ALDA + kt * 128 + t * 32 + quad * 8);
                else
                    a = *(const bf16x8*)(xb + (size_t)arow[m] * DFEAT + t * 32 + quad * 8);
                acc[m][0] = __builtin_amdgcn_mfma_f32_16x16x32_bf16(a, bq[t][0], acc[m][0], 0, 0, 0);
                acc[m][1] = __builtin_amdgcn_mfma_f32_16x16x32_bf16(a, bq[t][1], acc[m][1], 0, 0, 0);
            }
        }
    }

    #pragma unroll
    for (int g = 0; g < 2; ++g) {
        int c = wave * 32 + g * 16 + l16;
        float bv = bias[c];
        #pragma unroll
        for (int m = 0; m < 2; ++m) {
            #pragma unroll
            for (int reg = 0; reg < 4; ++reg) {
                int grow = row0 + m * 16 + quad * 4 + reg;
                if (grow < N)
                    out[(size_t)grow * DFEAT + c] = fmaxf(acc[m][g][reg] + bv, 0.f);
            }
        }
    }
}

extern "C" void kernel_launch(void* const* d_in, const int* in_sizes, int n_in,
                              void* d_out, int out_size, void* d_ws, size_t ws_size,
                              hipStream_t stream) {
    const float* x     = (const float*)d_in[0];
    const int*   src   = (const int*)  d_in[1];
    const int*   dst   = (const int*)  d_in[2];
    const float* coeff = (const float*)d_in[3];
    const float* bases = (const float*)d_in[4];
    const float* loopw = (const float*)d_in[5];
    const float* bias  = (const float*)d_in[6];
    float* out = (float*)d_out;

    const int N  = in_sizes[0] / DFEAT;            // 100000
    const int RE = in_sizes[1];                    // R*E = 1200000
    const int B  = in_sizes[4] / (DFEAT * DFEAT);  // 2
    const int R  = in_sizes[3] / B;                // 8
    const int E  = RE / R;                         // 150000
    const int NB = (N + 255) / 256;                // scan blocks (391)

    // workspace layout ([deg|status|ticket] contiguous -> ONE memset)
    char* ws = (char*)d_ws;
    size_t off = 0;
    auto alloc = [&](size_t bytes) { void* p = ws + off; off = (off + bytes + 255) & ~(size_t)255; return p; };
    int*      deg      = (int*)     alloc((size_t)R * N * sizeof(int));     // 3.2 MB
    unsigned* status   = (unsigned*)alloc((size_t)NB * sizeof(unsigned));
    int*      ticket   = (int*)     alloc(sizeof(int));
    size_t zeroBytes   = off;                       // covers deg+status+ticket
    int*      rowStart = (int*)     alloc((size_t)N * sizeof(int));
    int*      cursor   = (int*)     alloc((size_t)N * sizeof(int));
    ushort*   w2T      = (ushort*)  alloc((size_t)128 * 384 * sizeof(ushort));
    ushort*   xb       = (ushort*)  alloc((size_t)N * DFEAT * sizeof(ushort)); // 25.6 MB
    uint2*    recs     = (uint2*)   alloc((size_t)RE * sizeof(uint2));         // 9.6 MB

    hipMemsetAsync(deg, 0, zeroBytes, stream);
    fused_pre<<<4096, 256, 0, stream>>>(dst, deg, x, xb, bases, loopw, w2T,
                                        RE, E, N, N * 32);
    scan_onepass<<<NB, 256, 0, stream>>>(deg, rowStart, cursor, status, ticket, N);
    fill_kernel<<<(RE + 255) / 256, 256, 0, stream>>>(src, dst, coeff, deg, cursor,
                                                      recs, RE, E, N);
    gather_gemm<<<(N + 31) / 32, 256, 0, stream>>>(recs, rowStart, xb, w2T,
                                                   bias, out, N, RE);
}